// Round 1
// 2740.694 us; speedup vs baseline: 1.3869x; 1.3869x over previous
//
#include <hip/hip_runtime.h>
#include <stdint.h>

#define B_TOK 32768
#define DIM   1024
#define NEXP  8
#define NFR   4
#define HF    2048
#define HS    4096
#define CT    64          // m-tiles per chunk (8192 gathered rows)
#define NCH   9           // chunks: 9*64=576 tiles >= worst case 520
#define PADROWS 66560     // 520 tiles * 128

typedef __bf16 bf16;
typedef bf16  bf16x8 __attribute__((ext_vector_type(8)));
typedef bf16  bf16x4 __attribute__((ext_vector_type(4)));
typedef float f32x4  __attribute__((ext_vector_type(4)));

// LDS tile layout: 128 rows x 64 bf16, 16B chunk cc of row R lives at
// elem offset R*64 + ((cc ^ (R&7))*8)   -- XOR swizzle kills the 16-way
// bank conflict of the unswizzled row-major layout while staying
// compatible with global_load_lds' contiguous wave-uniform dest.
#define LDSOFF(R, CC) (((R) << 6) + ((((CC) ^ ((R) & 7))) << 3))

// ---------------------------------------------------------------------------
// Gating + RMS + x->bf16. One wave per row. Writes top-2 ids + weights.
// Gate dots in fp64 so top-k ranking matches numpy ref.
// NO global atomics here (they serialized at one cache line: 755us -> the
// histogram is now built by histoff_kernel from top2).
// ---------------------------------------------------------------------------
__global__ __launch_bounds__(256) void gate_kernel(
    const float* __restrict__ x, const float* __restrict__ gw_g,
    bf16* __restrict__ xb, float* __restrict__ rms,
    int* __restrict__ top2, float* __restrict__ c12) {
  __shared__ float gw[NEXP * DIM];
  for (int i = threadIdx.x; i < NEXP * DIM / 4; i += 256)
    *(f32x4*)(gw + i * 4) = *(const f32x4*)(gw_g + i * 4);
  __syncthreads();
  const int lane = threadIdx.x & 63;
  const int wave = threadIdx.x >> 6;
  const int row  = blockIdx.x * 4 + wave;
  const float* xr = x + (size_t)row * DIM;
  f32x4 xv[4];
#pragma unroll
  for (int i = 0; i < 4; i++) xv[i] = *(const f32x4*)(xr + lane * 4 + i * 256);
  float ss = 0.f;
  double dot[8] = {0, 0, 0, 0, 0, 0, 0, 0};
#pragma unroll
  for (int i = 0; i < 4; i++) {
#pragma unroll
    for (int c = 0; c < 4; c++) ss += xv[i][c] * xv[i][c];
#pragma unroll
    for (int e = 0; e < 8; e++) {
      const f32x4 g = *(const f32x4*)(gw + e * DIM + i * 256 + lane * 4);
#pragma unroll
      for (int c = 0; c < 4; c++) dot[e] += (double)xv[i][c] * (double)g[c];
    }
  }
#pragma unroll
  for (int off = 32; off > 0; off >>= 1) {
    ss += __shfl_xor(ss, off, 64);
#pragma unroll
    for (int e = 0; e < 8; e++) dot[e] += __shfl_xor(dot[e], off, 64);
  }
  const float rv = 1.0f / sqrtf(ss * (1.0f / DIM) + 1e-6f);
  if (lane == 0) rms[row] = rv;
  int i1 = 0; double m1 = dot[0];
#pragma unroll
  for (int e = 1; e < 8; e++) if (dot[e] > m1) { m1 = dot[e]; i1 = e; }
  int i2 = 0; double m2 = -1e300;
#pragma unroll
  for (int e = 0; e < 8; e++) if (e != i1 && dot[e] > m2) { m2 = dot[e]; i2 = e; }
  const double t  = exp(m2 - m1);
  if (lane == 0) {
    top2[row] = i1 | (i2 << 8);
    c12[2 * row]     = (float)(1.0 / (1.0 + t));
    c12[2 * row + 1] = (float)(t / (1.0 + t));
  }
#pragma unroll
  for (int i = 0; i < 4; i++) {
    bf16x4 o;
#pragma unroll
    for (int c = 0; c < 4; c++) o[c] = (bf16)xv[i][c];
    *(bf16x4*)(xb + (size_t)row * DIM + lane * 4 + i * 256) = o;
  }
}

// ---------------------------------------------------------------------------
// Histogram + offsets in one single-block kernel. Per-lane register counts
// (compile-time indexed), wave shuffle-reduce, 128 LDS atomics total, then
// thread 0 computes tile/row offsets. Replaces 65536 contended global
// atomics with zero.
// ---------------------------------------------------------------------------
__global__ __launch_bounds__(1024) void histoff_kernel(
    const int* __restrict__ top2, int* __restrict__ tileOff,
    int* __restrict__ rowOff) {
  __shared__ int h[8];
  if (threadIdx.x < 8) h[threadIdx.x] = 0;
  __syncthreads();
  int c[8] = {0, 0, 0, 0, 0, 0, 0, 0};
  for (int i = 0; i < B_TOK / 1024; i++) {
    const int pk = top2[threadIdx.x + i * 1024];
    const int e1 = pk & 255, e2 = pk >> 8;
#pragma unroll
    for (int e = 0; e < 8; e++) c[e] += (e1 == e) + (e2 == e);
  }
#pragma unroll
  for (int e = 0; e < 8; e++) {
#pragma unroll
    for (int off = 32; off > 0; off >>= 1) c[e] += __shfl_xor(c[e], off, 64);
  }
  if ((threadIdx.x & 63) == 0) {
#pragma unroll
    for (int e = 0; e < 8; e++) atomicAdd(&h[e], c[e]);
  }
  __syncthreads();
  if (threadIdx.x == 0) {
    int t = 0;
    for (int e = 0; e < 8; e++) {
      tileOff[e] = t;
      rowOff[e]  = t * 128;
      t += (h[e] + 127) >> 7;
    }
    tileOff[8] = t;
  }
}

// ---------------------------------------------------------------------------
// Assign: per-block LDS aggregation (LDS atomic return = intra-block slot),
// then ONE global atomic per expert per block (8*128=1024 total, each
// counter on its own 128B cache line) instead of 65536 same-line RMWs.
// ---------------------------------------------------------------------------
__global__ __launch_bounds__(256) void assign_kernel(
    const int* __restrict__ top2, const float* __restrict__ c12,
    const int* __restrict__ rowOff, int* __restrict__ cur,
    int* __restrict__ perm, float* __restrict__ cwg) {
  __shared__ int lhist[8];
  __shared__ int lbase[8];
  if (threadIdx.x < 8) lhist[threadIdx.x] = 0;
  __syncthreads();
  const int t = blockIdx.x * 256 + threadIdx.x;
  const int pk = top2[t];
  const int e1 = pk & 255, e2 = pk >> 8;
  const int p1 = atomicAdd(&lhist[e1], 1);
  const int p2 = atomicAdd(&lhist[e2], 1);
  __syncthreads();
  if (threadIdx.x < 8) {
    const int c = lhist[threadIdx.x];
    lbase[threadIdx.x] = c ? atomicAdd(&cur[threadIdx.x * 32], c) : 0;
  }
  __syncthreads();
  const int g1 = rowOff[e1] + lbase[e1] + p1;
  perm[g1] = t; cwg[g1] = c12[2 * t];
  const int g2 = rowOff[e2] + lbase[e2] + p2;
  perm[g2] = t; cwg[g2] = c12[2 * t + 1];
}

// ---------------------------------------------------------------------------
// Weight conversion fp32 -> bf16 (optionally column-scaled by fr_norm[e][d]).
// ---------------------------------------------------------------------------
__global__ __launch_bounds__(256) void cvt_kernel(
    const float* __restrict__ src, bf16* __restrict__ dst, int n4) {
  const int i = blockIdx.x * 256 + threadIdx.x;
  if (i >= n4) return;
  f32x4 v = *(const f32x4*)(src + (size_t)i * 4);
  *(bf16x4*)(dst + (size_t)i * 4) = __builtin_convertvector(v, bf16x4);
}

__global__ __launch_bounds__(256) void cvt_scaled_kernel(
    const float* __restrict__ src, const float* __restrict__ norm,
    bf16* __restrict__ dst, int n4) {
  const int i = blockIdx.x * 256 + threadIdx.x;
  if (i >= n4) return;
  const size_t f = (size_t)i * 4;
  f32x4 v = *(const f32x4*)(src + f);
  const float* np_ = norm + ((f >> 21) << 10) + (f & 1023);
#pragma unroll
  for (int c = 0; c < 4; c++) v[c] *= np_[c];
  *(bf16x4*)(dst + f) = __builtin_convertvector(v, bf16x4);
}

// ---------------------------------------------------------------------------
// Swizzled stage of a 128x64 bf16 tile into LDS (contiguous rows).
// ---------------------------------------------------------------------------
__device__ __forceinline__ void stage_sw(const bf16* __restrict__ g0, int ld,
                                         bf16* s0, int wave, int lane) {
  const int r = lane >> 3;
  const int c = (lane & 7) ^ r;
  const bf16* g = g0 + (size_t)(wave * 32 + r) * ld + c * 8;
  bf16* s = s0 + wave * 2048;
#pragma unroll
  for (int i = 0; i < 4; i++) {
    __builtin_amdgcn_global_load_lds(
        (const __attribute__((address_space(1))) void*)(uintptr_t)(g + (size_t)(i * 8) * ld),
        (__attribute__((address_space(3))) void*)(uintptr_t)(s + i * 512), 16, 0, 0);
  }
}

// ---------------------------------------------------------------------------
// GEMM1 (dual-B, gathered rows): H1 = A@B1^T, H3 = A@B3^T; G = silu(s*H1)*(s*H3).
// Block space: blockIdx.y = m-tile within chunk (global tile bt), blockIdx.x =
// n-tile (fractal uses 16 of 32). A rows come from xb via perm[] indirection.
// ---------------------------------------------------------------------------
__global__ __launch_bounds__(256, 2) void gemm1_kernel(
    const bf16* __restrict__ xb, const int* __restrict__ perm,
    const float* __restrict__ rms,
    const bf16* __restrict__ fw1, const bf16* __restrict__ fw3,
    const bf16* __restrict__ s1b, const bf16* __restrict__ s3b,
    const int* __restrict__ tileOff, bf16* __restrict__ G, int chunk) {
  const int bt = chunk * CT + blockIdx.y;
  int toff[9];
#pragma unroll
  for (int i = 0; i < 9; i++) toff[i] = tileOff[i];
  if (bt >= toff[8]) return;
  int e = 0;
#pragma unroll
  for (int i = 1; i < 8; i++) if (bt >= toff[i]) e = i;
  const bool isfr = (e < NFR);
  const int nt = isfr ? 16 : 32;
  if ((int)blockIdx.x >= nt) return;
  const bf16* B1 = isfr ? fw1 + (size_t)e * HF * DIM : s1b + (size_t)(e - NFR) * HS * DIM;
  const bf16* B3 = isfr ? fw3 + (size_t)e * HF * DIM : s3b + (size_t)(e - NFR) * HS * DIM;

  __shared__ __attribute__((aligned(16))) bf16 As[128 * 64];
  __shared__ __attribute__((aligned(16))) bf16 Bs1[128 * 64];
  __shared__ __attribute__((aligned(16))) bf16 Bs3[128 * 64];
  const int lane = threadIdx.x & 63, wave = threadIdx.x >> 6;
  const int wm = wave >> 1, wn = wave & 1;
  const int g0 = bt * 128;
  const int n0 = blockIdx.x * 128;

  // hoist gathered-token addresses for A staging (4 rows per lane)
  const int rA = lane >> 3;
  const int cA = (lane & 7) ^ rA;
  const bf16* Ag[4];
#pragma unroll
  for (int i = 0; i < 4; i++) {
    int tk = perm[g0 + wave * 32 + i * 8 + rA];
    if (tk < 0) tk = 0;
    Ag[i] = xb + (size_t)tk * DIM + cA * 8;
  }
  const bf16* B1b = B1 + (size_t)n0 * DIM;
  const bf16* B3b = B3 + (size_t)n0 * DIM;

  f32x4 acc1[4][4], acc3[4][4];
#pragma unroll
  for (int i = 0; i < 4; i++)
#pragma unroll
    for (int j = 0; j < 4; j++) {
      f32x4 z = {0.f, 0.f, 0.f, 0.f};
      acc1[i][j] = z; acc3[i][j] = z;
    }
  const int lr = lane & 15, lq = lane >> 4;
  bf16* Asw = As + wave * 2048;
  for (int k0 = 0; k0 < DIM; k0 += 64) {
#pragma unroll
    for (int i = 0; i < 4; i++) {
      __builtin_amdgcn_global_load_lds(
          (const __attribute__((address_space(1))) void*)(uintptr_t)(Ag[i] + k0),
          (__attribute__((address_space(3))) void*)(uintptr_t)(Asw + i * 512), 16, 0, 0);
    }
    stage_sw(B1b + k0, DIM, Bs1, wave, lane);
    stage_sw(B3b + k0, DIM, Bs3, wave, lane);
    __syncthreads();
#pragma unroll
    for (int ks = 0; ks < 2; ks++) {
      bf16x8 af[4], bf_[4], cf_[4];
#pragma unroll
      for (int mi = 0; mi < 4; mi++) {
        const int R = wm * 64 + mi * 16 + lr;
        af[mi] = *(const bf16x8*)(As + LDSOFF(R, ks * 4 + lq));
      }
#pragma unroll
      for (int ni = 0; ni < 4; ni++) {
        const int R = wn * 64 + ni * 16 + lr;
        bf_[ni] = *(const bf16x8*)(Bs1 + LDSOFF(R, ks * 4 + lq));
        cf_[ni] = *(const bf16x8*)(Bs3 + LDSOFF(R, ks * 4 + lq));
      }
#pragma unroll
      for (int mi = 0; mi < 4; mi++)
#pragma unroll
        for (int ni = 0; ni < 4; ni++) {
          acc1[mi][ni] = __builtin_amdgcn_mfma_f32_16x16x32_bf16(af[mi], bf_[ni], acc1[mi][ni], 0, 0, 0);
          acc3[mi][ni] = __builtin_amdgcn_mfma_f32_16x16x32_bf16(af[mi], cf_[ni], acc3[mi][ni], 0, 0, 0);
        }
    }
    __syncthreads();
  }
  // C/D layout col=lane&15, row=(lane>>4)*4+r  [m89/m91]
#pragma unroll
  for (int mi = 0; mi < 4; mi++) {
#pragma unroll
    for (int r = 0; r < 4; r++) {
      const int row_l = wm * 64 + mi * 16 + lq * 4 + r;
      float s = 1.0f;
      if (isfr) {
        int tok = perm[g0 + row_l];
        s = rms[tok < 0 ? 0 : tok];
      }
      bf16* Grow = G + (size_t)(blockIdx.y * 128 + row_l) * HS;
#pragma unroll
      for (int ni = 0; ni < 4; ni++) {
        const int col = n0 + wn * 64 + ni * 16 + lr;
        const float h1 = acc1[mi][ni][r] * s;
        const float h3 = acc3[mi][ni][r] * s;
        Grow[col] = (bf16)(h1 / (1.0f + __expf(-h1)) * h3);
      }
    }
  }
}

// ---------------------------------------------------------------------------
// GEMM2: Y = G @ W2^T (N=1024), scatter-add to out with fused epilogue:
//   fractal: out[tok] += cw*(gamma[col]*(rms[tok]*x*norm[col] + Y) + x)
//   plain:   out[tok] += cw*Y
// ---------------------------------------------------------------------------
__global__ __launch_bounds__(256, 2) void gemm2_kernel(
    const bf16* __restrict__ G, const int* __restrict__ perm,
    const float* __restrict__ cwg, const float* __restrict__ rms,
    const float* __restrict__ gamma_all, const float* __restrict__ norm_all,
    const float* __restrict__ x,
    const bf16* __restrict__ fw2, const bf16* __restrict__ s2b,
    const int* __restrict__ tileOff, float* __restrict__ out, int chunk) {
  const int bt = chunk * CT + blockIdx.y;
  int toff[9];
#pragma unroll
  for (int i = 0; i < 9; i++) toff[i] = tileOff[i];
  if (bt >= toff[8]) return;
  int e = 0;
#pragma unroll
  for (int i = 1; i < 8; i++) if (bt >= toff[i]) e = i;
  const bool isfr = (e < NFR);
  const int K = isfr ? HF : HS;
  const bf16* Bw = isfr ? fw2 + (size_t)e * DIM * HF : s2b + (size_t)(e - NFR) * DIM * HS;

  __shared__ __attribute__((aligned(16))) bf16 As[128 * 64];
  __shared__ __attribute__((aligned(16))) bf16 Bs[128 * 64];
  const int lane = threadIdx.x & 63, wave = threadIdx.x >> 6;
  const int wm = wave >> 1, wn = wave & 1;
  const int n0 = blockIdx.x * 128;
  f32x4 acc[4][4];
#pragma unroll
  for (int i = 0; i < 4; i++)
#pragma unroll
    for (int j = 0; j < 4; j++) { f32x4 z = {0.f, 0.f, 0.f, 0.f}; acc[i][j] = z; }
  const bf16* Ab = G + (size_t)(blockIdx.y * 128) * HS;   // chunk-local rows, stride 4096
  const bf16* Bb = Bw + (size_t)n0 * K;
  const int lr = lane & 15, lq = lane >> 4;
  for (int k0 = 0; k0 < K; k0 += 64) {
    stage_sw(Ab + k0, HS, As, wave, lane);
    stage_sw(Bb + k0, K, Bs, wave, lane);
    __syncthreads();
#pragma unroll
    for (int ks = 0; ks < 2; ks++) {
      bf16x8 af[4], bf_[4];
#pragma unroll
      for (int mi = 0; mi < 4; mi++) {
        const int R = wm * 64 + mi * 16 + lr;
        af[mi] = *(const bf16x8*)(As + LDSOFF(R, ks * 4 + lq));
      }
#pragma unroll
      for (int ni = 0; ni < 4; ni++) {
        const int R = wn * 64 + ni * 16 + lr;
        bf_[ni] = *(const bf16x8*)(Bs + LDSOFF(R, ks * 4 + lq));
      }
#pragma unroll
      for (int mi = 0; mi < 4; mi++)
#pragma unroll
        for (int ni = 0; ni < 4; ni++)
          acc[mi][ni] = __builtin_amdgcn_mfma_f32_16x16x32_bf16(af[mi], bf_[ni], acc[mi][ni], 0, 0, 0);
    }
    __syncthreads();
  }
#pragma unroll
  for (int mi = 0; mi < 4; mi++) {
#pragma unroll
    for (int r = 0; r < 4; r++) {
      const int row_l = wm * 64 + mi * 16 + lq * 4 + r;
      const int g_row = bt * 128 + row_l;
      const int tok = perm[g_row];
      if (tok < 0) continue;
      const float cw = cwg[g_row];
      const float rv = rms[tok];
#pragma unroll
      for (int ni = 0; ni < 4; ni++) {
        const int col = n0 + wn * 64 + ni * 16 + lr;
        const float a = acc[mi][ni][r];
        float res;
        if (isfr) {
          const float xvv = x[(size_t)tok * DIM + col];
          res = cw * (gamma_all[e * DIM + col] * (rv * xvv * norm_all[e * DIM + col] + a) + xvv);
        } else {
          res = cw * a;
        }
        atomicAdd(&out[(size_t)tok * DIM + col], res);
      }
    }
  }
}

// ---------------------------------------------------------------------------
extern "C" void kernel_launch(void* const* d_in, const int* in_sizes, int n_in,
                              void* d_out, int out_size, void* d_ws, size_t ws_size,
                              hipStream_t stream) {
  const float* x        = (const float*)d_in[0];
  const float* gate_w   = (const float*)d_in[1];
  const float* fr_norm  = (const float*)d_in[2];
  const float* fr_gamma = (const float*)d_in[3];
  const float* fr_w1    = (const float*)d_in[4];
  const float* fr_w2    = (const float*)d_in[5];
  const float* fr_w3    = (const float*)d_in[6];
  const float* sw_w1    = (const float*)d_in[7];
  const float* sw_w2    = (const float*)d_in[8];
  const float* sw_w3    = (const float*)d_in[9];
  float* out = (float*)d_out;

  char* ws = (char*)d_ws;                        // ~273 MB total (<= round-0 proven)
  bf16*  xb    = (bf16*)(ws);                    // 64 MB
  bf16*  fw1   = (bf16*)(ws + 67108864);         // 16 MB (fr_w1 * fr_norm)
  bf16*  fw3   = (bf16*)(ws + 83886080);         // 16 MB (fr_w3 * fr_norm)
  bf16*  fw2   = (bf16*)(ws + 100663296);        // 16 MB
  bf16*  s1b   = (bf16*)(ws + 117440512);        // 32 MB
  bf16*  s3b   = (bf16*)(ws + 150994944);        // 32 MB
  bf16*  s2b   = (bf16*)(ws + 184549376);        // 32 MB
  bf16*  G     = (bf16*)(ws + 218103808);        // 64 MB (8192 x 4096)
  float* rmsb  = (float*)(ws + 285212672);       // 128 KB
  int*   top2  = (int*)  (ws + 285343744);       // 128 KB
  float* c12   = (float*)(ws + 285474816);       // 256 KB
  int*   perm  = (int*)  (ws + 285736960);       // 260 KB
  float* cwg   = (float*)(ws + 286003200);       // 260 KB
  int*   cur   = (int*)  (ws + 286269440);       // 1 KB (8 counters, 128B apart)
  int*   tileOff = (int*)(ws + 286270464);       // 36 B
  int*   rowOff  = (int*)(ws + 286270500);       // 32 B

  hipMemsetAsync(d_out, 0, (size_t)out_size * sizeof(float), stream);
  hipMemsetAsync(cur, 0, 1024, stream);
  hipMemsetAsync(perm, 0xFF, PADROWS * 4, stream);

  gate_kernel<<<B_TOK / 4, 256, 0, stream>>>(x, gate_w, xb, rmsb, top2, c12);
  histoff_kernel<<<1, 1024, 0, stream>>>(top2, tileOff, rowOff);
  assign_kernel<<<B_TOK / 256, 256, 0, stream>>>(top2, c12, rowOff, cur, perm, cwg);

  cvt_scaled_kernel<<<8192, 256, 0, stream>>>(fr_w1, fr_norm, fw1, 2097152);
  cvt_scaled_kernel<<<8192, 256, 0, stream>>>(fr_w3, fr_norm, fw3, 2097152);
  cvt_kernel<<<8192, 256, 0, stream>>>(fr_w2, fw2, 2097152);
  cvt_kernel<<<16384, 256, 0, stream>>>(sw_w1, s1b, 4194304);
  cvt_kernel<<<16384, 256, 0, stream>>>(sw_w3, s3b, 4194304);
  cvt_kernel<<<16384, 256, 0, stream>>>(sw_w2, s2b, 4194304);

  for (int c = 0; c < NCH; c++) {
    gemm1_kernel<<<dim3(32, CT), 256, 0, stream>>>(
        xb, perm, rmsb, fw1, fw3, s1b, s3b, tileOff, G, c);
    gemm2_kernel<<<dim3(8, CT), 256, 0, stream>>>(
        G, perm, cwg, rmsb, fr_gamma, fr_norm, x, fw2, s2b, tileOff, out, c);
  }
}

// Round 2
// 2728.276 us; speedup vs baseline: 1.3932x; 1.0046x over previous
//
#include <hip/hip_runtime.h>
#include <stdint.h>

#define B_TOK 32768
#define DIM   1024
#define NEXP  8
#define NFR   4
#define HF    2048
#define HS    4096
#define CT1   32          // 256-row m-tiles per chunk (8192 gathered rows)
#define CT2   64          // 128-row m-tiles per chunk (gemm2)
#define NCH   9           // chunks: 9*32=288 256-tiles >= worst case 264
#define PADROWS 67584     // 264 tiles * 256

typedef __bf16 bf16;
typedef bf16  bf16x8 __attribute__((ext_vector_type(8)));
typedef bf16  bf16x4 __attribute__((ext_vector_type(4)));
typedef float f32x4  __attribute__((ext_vector_type(4)));

// LDS tile layout: R rows x 64 bf16, 16B chunk cc of row R lives at
// elem offset R*64 + ((cc ^ (R&7))*8)   -- XOR swizzle kills the 16-way
// bank conflict of the unswizzled row-major layout while staying
// compatible with global_load_lds' contiguous wave-uniform dest.
#define LDSOFF(R, CC) (((R) << 6) + ((((CC) ^ ((R) & 7))) << 3))

// ---------------------------------------------------------------------------
// Gating + RMS + x->bf16. One wave per row. Writes top-2 ids + weights.
// Gate dots in fp64 so top-k ranking matches numpy ref.
// ---------------------------------------------------------------------------
__global__ __launch_bounds__(256) void gate_kernel(
    const float* __restrict__ x, const float* __restrict__ gw_g,
    bf16* __restrict__ xb, float* __restrict__ rms,
    int* __restrict__ top2, float* __restrict__ c12) {
  __shared__ float gw[NEXP * DIM];
  for (int i = threadIdx.x; i < NEXP * DIM / 4; i += 256)
    *(f32x4*)(gw + i * 4) = *(const f32x4*)(gw_g + i * 4);
  __syncthreads();
  const int lane = threadIdx.x & 63;
  const int wave = threadIdx.x >> 6;
  const int row  = blockIdx.x * 4 + wave;
  const float* xr = x + (size_t)row * DIM;
  f32x4 xv[4];
#pragma unroll
  for (int i = 0; i < 4; i++) xv[i] = *(const f32x4*)(xr + lane * 4 + i * 256);
  float ss = 0.f;
  double dot[8] = {0, 0, 0, 0, 0, 0, 0, 0};
#pragma unroll
  for (int i = 0; i < 4; i++) {
#pragma unroll
    for (int c = 0; c < 4; c++) ss += xv[i][c] * xv[i][c];
#pragma unroll
    for (int e = 0; e < 8; e++) {
      const f32x4 g = *(const f32x4*)(gw + e * DIM + i * 256 + lane * 4);
#pragma unroll
      for (int c = 0; c < 4; c++) dot[e] += (double)xv[i][c] * (double)g[c];
    }
  }
#pragma unroll
  for (int off = 32; off > 0; off >>= 1) {
    ss += __shfl_xor(ss, off, 64);
#pragma unroll
    for (int e = 0; e < 8; e++) dot[e] += __shfl_xor(dot[e], off, 64);
  }
  const float rv = 1.0f / sqrtf(ss * (1.0f / DIM) + 1e-6f);
  if (lane == 0) rms[row] = rv;
  int i1 = 0; double m1 = dot[0];
#pragma unroll
  for (int e = 1; e < 8; e++) if (dot[e] > m1) { m1 = dot[e]; i1 = e; }
  int i2 = 0; double m2 = -1e300;
#pragma unroll
  for (int e = 0; e < 8; e++) if (e != i1 && dot[e] > m2) { m2 = dot[e]; i2 = e; }
  const double t  = exp(m2 - m1);
  if (lane == 0) {
    top2[row] = i1 | (i2 << 8);
    c12[2 * row]     = (float)(1.0 / (1.0 + t));
    c12[2 * row + 1] = (float)(t / (1.0 + t));
  }
#pragma unroll
  for (int i = 0; i < 4; i++) {
    bf16x4 o;
#pragma unroll
    for (int c = 0; c < 4; c++) o[c] = (bf16)xv[i][c];
    *(bf16x4*)(xb + (size_t)row * DIM + lane * 4 + i * 256) = o;
  }
}

// ---------------------------------------------------------------------------
// Histogram + offsets (256-row tiles for gemm1, derived 128-row tiles for
// gemm2). Per-lane register counts, wave shuffle-reduce, 128 LDS atomics.
// ---------------------------------------------------------------------------
__global__ __launch_bounds__(1024) void histoff_kernel(
    const int* __restrict__ top2, int* __restrict__ tileOff256,
    int* __restrict__ tileOff128, int* __restrict__ rowOff) {
  __shared__ int h[8];
  if (threadIdx.x < 8) h[threadIdx.x] = 0;
  __syncthreads();
  int c[8] = {0, 0, 0, 0, 0, 0, 0, 0};
  for (int i = 0; i < B_TOK / 1024; i++) {
    const int pk = top2[threadIdx.x + i * 1024];
    const int e1 = pk & 255, e2 = pk >> 8;
#pragma unroll
    for (int e = 0; e < 8; e++) c[e] += (e1 == e) + (e2 == e);
  }
#pragma unroll
  for (int e = 0; e < 8; e++) {
#pragma unroll
    for (int off = 32; off > 0; off >>= 1) c[e] += __shfl_xor(c[e], off, 64);
  }
  if ((threadIdx.x & 63) == 0) {
#pragma unroll
    for (int e = 0; e < 8; e++) atomicAdd(&h[e], c[e]);
  }
  __syncthreads();
  if (threadIdx.x == 0) {
    int t = 0;
    for (int e = 0; e < 8; e++) {
      tileOff256[e] = t;
      tileOff128[e] = 2 * t;
      rowOff[e]     = t * 256;
      t += (h[e] + 255) >> 8;
    }
    tileOff256[8] = t;
    tileOff128[8] = 2 * t;
  }
}

// ---------------------------------------------------------------------------
// Assign: per-block LDS aggregation, then ONE global atomic per expert per
// block (each counter on its own 128B cache line).
// ---------------------------------------------------------------------------
__global__ __launch_bounds__(256) void assign_kernel(
    const int* __restrict__ top2, const float* __restrict__ c12,
    const int* __restrict__ rowOff, int* __restrict__ cur,
    int* __restrict__ perm, float* __restrict__ cwg) {
  __shared__ int lhist[8];
  __shared__ int lbase[8];
  if (threadIdx.x < 8) lhist[threadIdx.x] = 0;
  __syncthreads();
  const int t = blockIdx.x * 256 + threadIdx.x;
  const int pk = top2[t];
  const int e1 = pk & 255, e2 = pk >> 8;
  const int p1 = atomicAdd(&lhist[e1], 1);
  const int p2 = atomicAdd(&lhist[e2], 1);
  __syncthreads();
  if (threadIdx.x < 8) {
    const int c = lhist[threadIdx.x];
    lbase[threadIdx.x] = c ? atomicAdd(&cur[threadIdx.x * 32], c) : 0;
  }
  __syncthreads();
  const int g1 = rowOff[e1] + lbase[e1] + p1;
  perm[g1] = t; cwg[g1] = c12[2 * t];
  const int g2 = rowOff[e2] + lbase[e2] + p2;
  perm[g2] = t; cwg[g2] = c12[2 * t + 1];
}

// ---------------------------------------------------------------------------
// Weight conversion fp32 -> bf16.
// cvt_kernel: plain (for w2).
// cvt_inter_*: build interleaved B' for gemm1 -- 16-row blocks alternating
// w1 (even) / w3 (odd), so one GEMM produces (h1,h3) in adjacent 16-col
// accumulator fragments. Fractal variant folds the RMSNorm column scale.
// ---------------------------------------------------------------------------
__global__ __launch_bounds__(256) void cvt_kernel(
    const float* __restrict__ src, bf16* __restrict__ dst, int n4) {
  const int i = blockIdx.x * 256 + threadIdx.x;
  if (i >= n4) return;
  f32x4 v = *(const f32x4*)(src + (size_t)i * 4);
  *(bf16x4*)(dst + (size_t)i * 4) = __builtin_convertvector(v, bf16x4);
}

__global__ __launch_bounds__(256) void cvt_inter_fr(
    const float* __restrict__ w1, const float* __restrict__ w3,
    const float* __restrict__ norm, bf16* __restrict__ dst) {
  const int i = blockIdx.x * 256 + threadIdx.x;   // 4*4096*256 f32x4 groups
  const int col4 = i & 255;
  const int rp   = (i >> 8) & 4095;
  const int e    = i >> 20;
  const int blk  = rp >> 4;
  const int sr   = ((blk >> 1) << 4) + (rp & 15);
  const float* src = (blk & 1) ? w3 : w1;
  f32x4 v  = *(const f32x4*)(src + ((size_t)e * HF + sr) * DIM + col4 * 4);
  f32x4 nv = *(const f32x4*)(norm + e * DIM + col4 * 4);
#pragma unroll
  for (int c = 0; c < 4; c++) v[c] *= nv[c];
  *(bf16x4*)(dst + ((size_t)e * 4096 + rp) * DIM + col4 * 4) =
      __builtin_convertvector(v, bf16x4);
}

__global__ __launch_bounds__(256) void cvt_inter_sw(
    const float* __restrict__ w1, const float* __restrict__ w3,
    bf16* __restrict__ dst) {
  const int i = blockIdx.x * 256 + threadIdx.x;   // 4*8192*256 f32x4 groups
  const int col4 = i & 255;
  const int rp   = (i >> 8) & 8191;
  const int e    = i >> 21;
  const int blk  = rp >> 4;
  const int sr   = ((blk >> 1) << 4) + (rp & 15);
  const float* src = (blk & 1) ? w3 : w1;
  f32x4 v = *(const f32x4*)(src + ((size_t)e * HS + sr) * DIM + col4 * 4);
  *(bf16x4*)(dst + ((size_t)e * 8192 + rp) * DIM + col4 * 4) =
      __builtin_convertvector(v, bf16x4);
}

// ---------------------------------------------------------------------------
// Swizzled stage of a (32*nwaves)x64 bf16 tile into LDS, one wave = 32 rows.
// ---------------------------------------------------------------------------
__device__ __forceinline__ void stage_sw(const bf16* __restrict__ g0, int ld,
                                         bf16* s0, int wave, int lane) {
  const int r = lane >> 3;
  const int c = (lane & 7) ^ r;
  const bf16* g = g0 + (size_t)(wave * 32 + r) * ld + c * 8;
  bf16* s = s0 + wave * 2048;
#pragma unroll
  for (int i = 0; i < 4; i++) {
    __builtin_amdgcn_global_load_lds(
        (const __attribute__((address_space(1))) void*)(uintptr_t)(g + (size_t)(i * 8) * ld),
        (__attribute__((address_space(3))) void*)(uintptr_t)(s + i * 512), 16, 0, 0);
  }
}

// ---------------------------------------------------------------------------
// GEMM1: 256x256 tile, BK=64, 8 waves (2M x 4N), double-buffered LDS
// (128 KB), 2-phase pipeline: stage next K-tile while computing current,
// one barrier per K-step. B' is the 16-row-interleaved (w1|w3) matrix, so
// acc n-frags alternate h1/h3 of the same G column block.
// G = silu(s*H1)*(s*H3), s = rms for fractal experts.
// ---------------------------------------------------------------------------
__global__ __launch_bounds__(512, 2) void gemm1_kernel(
    const bf16* __restrict__ xb, const int* __restrict__ perm,
    const float* __restrict__ rms,
    const bf16* __restrict__ fwi, const bf16* __restrict__ swi,
    const int* __restrict__ tileOff256, bf16* __restrict__ G, int chunk) {
  const int bt = chunk * CT1 + blockIdx.y;
  int toff[9];
#pragma unroll
  for (int i = 0; i < 9; i++) toff[i] = tileOff256[i];
  if (bt >= toff[8]) return;
  int e = 0;
#pragma unroll
  for (int i = 1; i < 8; i++) if (bt >= toff[i]) e = i;
  const bool isfr = (e < NFR);
  const int nt = isfr ? 16 : 32;            // N' = 4096 (fr) / 8192 (sw)
  if ((int)blockIdx.x >= nt) return;
  const bf16* Bp = isfr ? fwi + (size_t)e * 4096 * DIM
                        : swi + (size_t)(e - NFR) * 8192 * DIM;

  __shared__ __attribute__((aligned(16))) bf16 As[2 * 16384];
  __shared__ __attribute__((aligned(16))) bf16 Bs[2 * 16384];
  const int lane = threadIdx.x & 63, wave = threadIdx.x >> 6;
  const int wm = wave >> 2, wn = wave & 3;
  const int g0  = bt * 256;
  const int n0p = blockIdx.x * 256;         // B' row offset

  // staging source pointers (gathered A rows; regular B' rows)
  const int rA = lane >> 3;
  const int cA = (lane & 7) ^ rA;
  const bf16* Ag[4];
#pragma unroll
  for (int i = 0; i < 4; i++) {
    int tk = perm[g0 + wave * 32 + i * 8 + rA];
    if (tk < 0) tk = 0;
    Ag[i] = xb + (size_t)tk * DIM + cA * 8;
  }
  const bf16* Bg = Bp + (size_t)(n0p + wave * 32 + rA) * DIM + cA * 8;

  f32x4 acc[8][4];
#pragma unroll
  for (int i = 0; i < 8; i++)
#pragma unroll
    for (int j = 0; j < 4; j++) { f32x4 z = {0.f, 0.f, 0.f, 0.f}; acc[i][j] = z; }
  const int lr = lane & 15, lq = lane >> 4;

  auto stage = [&](int buf, int k0) {
    bf16* sa = As + buf * 16384 + wave * 2048;
    bf16* sb = Bs + buf * 16384 + wave * 2048;
#pragma unroll
    for (int i = 0; i < 4; i++) {
      __builtin_amdgcn_global_load_lds(
          (const __attribute__((address_space(1))) void*)(uintptr_t)(Ag[i] + k0),
          (__attribute__((address_space(3))) void*)(uintptr_t)(sa + i * 512), 16, 0, 0);
    }
#pragma unroll
    for (int i = 0; i < 4; i++) {
      __builtin_amdgcn_global_load_lds(
          (const __attribute__((address_space(1))) void*)(uintptr_t)(Bg + (size_t)(i * 8) * DIM + k0),
          (__attribute__((address_space(3))) void*)(uintptr_t)(sb + i * 512), 16, 0, 0);
    }
  };
  auto compute = [&](int buf) {
    const bf16* Ab = As + buf * 16384;
    const bf16* Bb = Bs + buf * 16384;
#pragma unroll
    for (int ks = 0; ks < 2; ks++) {
      bf16x8 af[8], bfv[4];
#pragma unroll
      for (int mi = 0; mi < 8; mi++)
        af[mi] = *(const bf16x8*)(Ab + LDSOFF(wm * 128 + mi * 16 + lr, ks * 4 + lq));
#pragma unroll
      for (int ni = 0; ni < 4; ni++)
        bfv[ni] = *(const bf16x8*)(Bb + LDSOFF(wn * 64 + ni * 16 + lr, ks * 4 + lq));
      __builtin_amdgcn_s_setprio(1);
#pragma unroll
      for (int mi = 0; mi < 8; mi++)
#pragma unroll
        for (int ni = 0; ni < 4; ni++)
          acc[mi][ni] = __builtin_amdgcn_mfma_f32_16x16x32_bf16(af[mi], bfv[ni], acc[mi][ni], 0, 0, 0);
      __builtin_amdgcn_s_setprio(0);
    }
  };

  stage(0, 0);
  __syncthreads();
  int k = 64;
#pragma unroll 1
  for (int t = 0; t < 7; t++) {
    stage(1, k); compute(0); __syncthreads(); k += 64;
    stage(0, k); compute(1); __syncthreads(); k += 64;
  }
  stage(1, k); compute(0); __syncthreads();
  compute(1);

  // epilogue: C/D layout col=lane&15, row=(lane>>4)*4+r [m89/m91]
  const int gh = n0p >> 1;                   // base G column of this block
#pragma unroll
  for (int mi = 0; mi < 8; mi++) {
#pragma unroll
    for (int r = 0; r < 4; r++) {
      const int row_l = wm * 128 + mi * 16 + lq * 4 + r;
      float s = 1.0f;
      if (isfr) {
        int tok = perm[g0 + row_l];
        s = rms[tok < 0 ? 0 : tok];
      }
      bf16* Grow = G + (size_t)(blockIdx.y * 256 + row_l) * HS;
#pragma unroll
      for (int nh = 0; nh < 2; nh++) {
        const float h1 = acc[mi][2 * nh][r] * s;
        const float h3 = acc[mi][2 * nh + 1][r] * s;
        const int col = gh + wn * 32 + nh * 16 + lr;
        Grow[col] = (bf16)(h1 / (1.0f + __expf(-h1)) * h3);
      }
    }
  }
}

// ---------------------------------------------------------------------------
// GEMM2: Y = G @ W2^T (N=1024), 128x128 tiles, scatter-add to out with fused
// epilogue:
//   fractal: out[tok] += cw*(gamma[col]*(rms[tok]*x*norm[col] + Y) + x)
//   plain:   out[tok] += cw*Y
// ---------------------------------------------------------------------------
__global__ __launch_bounds__(256, 2) void gemm2_kernel(
    const bf16* __restrict__ G, const int* __restrict__ perm,
    const float* __restrict__ cwg, const float* __restrict__ rms,
    const float* __restrict__ gamma_all, const float* __restrict__ norm_all,
    const float* __restrict__ x,
    const bf16* __restrict__ fw2, const bf16* __restrict__ s2b,
    const int* __restrict__ tileOff128, float* __restrict__ out, int chunk) {
  const int bt = chunk * CT2 + blockIdx.y;
  int toff[9];
#pragma unroll
  for (int i = 0; i < 9; i++) toff[i] = tileOff128[i];
  if (bt >= toff[8]) return;
  int e = 0;
#pragma unroll
  for (int i = 1; i < 8; i++) if (bt >= toff[i]) e = i;
  const bool isfr = (e < NFR);
  const int K = isfr ? HF : HS;
  const bf16* Bw = isfr ? fw2 + (size_t)e * DIM * HF : s2b + (size_t)(e - NFR) * DIM * HS;

  __shared__ __attribute__((aligned(16))) bf16 As[128 * 64];
  __shared__ __attribute__((aligned(16))) bf16 Bs[128 * 64];
  const int lane = threadIdx.x & 63, wave = threadIdx.x >> 6;
  const int wm = wave >> 1, wn = wave & 1;
  const int n0 = blockIdx.x * 128;
  f32x4 acc[4][4];
#pragma unroll
  for (int i = 0; i < 4; i++)
#pragma unroll
    for (int j = 0; j < 4; j++) { f32x4 z = {0.f, 0.f, 0.f, 0.f}; acc[i][j] = z; }
  const bf16* Ab = G + (size_t)(blockIdx.y * 128) * HS;   // chunk-local rows
  const bf16* Bb = Bw + (size_t)n0 * K;
  const int lr = lane & 15, lq = lane >> 4;
  for (int k0 = 0; k0 < K; k0 += 64) {
    stage_sw(Ab + k0, HS, As, wave, lane);
    stage_sw(Bb + k0, K, Bs, wave, lane);
    __syncthreads();
#pragma unroll
    for (int ks = 0; ks < 2; ks++) {
      bf16x8 af[4], bf_[4];
#pragma unroll
      for (int mi = 0; mi < 4; mi++) {
        const int R = wm * 64 + mi * 16 + lr;
        af[mi] = *(const bf16x8*)(As + LDSOFF(R, ks * 4 + lq));
      }
#pragma unroll
      for (int ni = 0; ni < 4; ni++) {
        const int R = wn * 64 + ni * 16 + lr;
        bf_[ni] = *(const bf16x8*)(Bs + LDSOFF(R, ks * 4 + lq));
      }
#pragma unroll
      for (int mi = 0; mi < 4; mi++)
#pragma unroll
        for (int ni = 0; ni < 4; ni++)
          acc[mi][ni] = __builtin_amdgcn_mfma_f32_16x16x32_bf16(af[mi], bf_[ni], acc[mi][ni], 0, 0, 0);
    }
    __syncthreads();
  }
#pragma unroll
  for (int mi = 0; mi < 4; mi++) {
#pragma unroll
    for (int r = 0; r < 4; r++) {
      const int row_l = wm * 64 + mi * 16 + lq * 4 + r;
      const int g_row = bt * 128 + row_l;
      const int tok = perm[g_row];
      if (tok < 0) continue;
      const float cw = cwg[g_row];
      const float rv = rms[tok];
#pragma unroll
      for (int ni = 0; ni < 4; ni++) {
        const int col = n0 + wn * 64 + ni * 16 + lr;
        const float a = acc[mi][ni][r];
        float res;
        if (isfr) {
          const float xvv = x[(size_t)tok * DIM + col];
          res = cw * (gamma_all[e * DIM + col] * (rv * xvv * norm_all[e * DIM + col] + a) + xvv);
        } else {
          res = cw * a;
        }
        atomicAdd(&out[(size_t)tok * DIM + col], res);
      }
    }
  }
}

// ---------------------------------------------------------------------------
extern "C" void kernel_launch(void* const* d_in, const int* in_sizes, int n_in,
                              void* d_out, int out_size, void* d_ws, size_t ws_size,
                              hipStream_t stream) {
  const float* x        = (const float*)d_in[0];
  const float* gate_w   = (const float*)d_in[1];
  const float* fr_norm  = (const float*)d_in[2];
  const float* fr_gamma = (const float*)d_in[3];
  const float* fr_w1    = (const float*)d_in[4];
  const float* fr_w2    = (const float*)d_in[5];
  const float* fr_w3    = (const float*)d_in[6];
  const float* sw_w1    = (const float*)d_in[7];
  const float* sw_w2    = (const float*)d_in[8];
  const float* sw_w3    = (const float*)d_in[9];
  float* out = (float*)d_out;

  char* ws = (char*)d_ws;                        // ~286.3 MB total
  bf16*  xb    = (bf16*)(ws);                    // 64 MB
  bf16*  fwi   = (bf16*)(ws + 67108864);         // 32 MB (fr w1|w3 interleaved, *norm)
  bf16*  fw2   = (bf16*)(ws + 100663296);        // 16 MB
  bf16*  swi   = (bf16*)(ws + 117440512);        // 64 MB (sw w1|w3 interleaved)
  bf16*  s2b   = (bf16*)(ws + 184549376);        // 32 MB
  bf16*  G     = (bf16*)(ws + 218103808);        // 64 MB (8192 x 4096)
  float* rmsb  = (float*)(ws + 285212672);       // 128 KB
  int*   top2  = (int*)  (ws + 285343744);       // 128 KB
  float* c12   = (float*)(ws + 285474816);       // 256 KB
  int*   perm  = (int*)  (ws + 285736960);       // 264 KB
  float* cwg   = (float*)(ws + 286007296);       // 264 KB
  int*   cur   = (int*)  (ws + 286277632);       // 1 KB (8 counters, 128B apart)
  int*   tileOff256 = (int*)(ws + 286278656);    // 64 B
  int*   tileOff128 = (int*)(ws + 286278720);    // 64 B
  int*   rowOff     = (int*)(ws + 286278784);    // 64 B

  hipMemsetAsync(d_out, 0, (size_t)out_size * sizeof(float), stream);
  hipMemsetAsync(cur, 0, 1024, stream);
  hipMemsetAsync(perm, 0xFF, PADROWS * 4, stream);

  gate_kernel<<<B_TOK / 4, 256, 0, stream>>>(x, gate_w, xb, rmsb, top2, c12);
  histoff_kernel<<<1, 1024, 0, stream>>>(top2, tileOff256, tileOff128, rowOff);
  assign_kernel<<<B_TOK / 256, 256, 0, stream>>>(top2, c12, rowOff, cur, perm, cwg);

  cvt_inter_fr<<<16384, 256, 0, stream>>>(fr_w1, fr_w3, fr_norm, fwi);
  cvt_kernel<<<8192, 256, 0, stream>>>(fr_w2, fw2, 2097152);
  cvt_inter_sw<<<32768, 256, 0, stream>>>(sw_w1, sw_w3, swi);
  cvt_kernel<<<16384, 256, 0, stream>>>(sw_w2, s2b, 4194304);

  for (int c = 0; c < NCH; c++) {
    gemm1_kernel<<<dim3(32, CT1), 512, 0, stream>>>(
        xb, perm, rmsb, fwi, swi, tileOff256, G, c);
    gemm2_kernel<<<dim3(8, CT2), 256, 0, stream>>>(
        G, perm, cwg, rmsb, fr_gamma, fr_norm, x, fw2, s2b, tileOff128, out, c);
  }
}

// Round 3
// 2642.290 us; speedup vs baseline: 1.4385x; 1.0325x over previous
//
#include <hip/hip_runtime.h>
#include <stdint.h>

#define B_TOK 32768
#define DIM   1024
#define NEXP  8
#define NFR   4
#define HF    2048
#define HS    4096
#define CT1   32          // 256-row m-tiles per chunk (8192 gathered rows)
#define CT2   64          // 128-row m-tiles per chunk (gemm2)
#define NCH   9           // chunks: 9*32=288 256-tiles >= worst case 264
#define PADROWS 67584     // 264 tiles * 256

typedef __bf16 bf16;
typedef bf16  bf16x8 __attribute__((ext_vector_type(8)));
typedef bf16  bf16x4 __attribute__((ext_vector_type(4)));
typedef float f32x4  __attribute__((ext_vector_type(4)));

// LDS tile layout: R rows x 64 bf16, 16B chunk cc of row R lives at
// elem offset R*64 + ((cc ^ (R&7))*8)   -- XOR swizzle kills the 16-way
// bank conflict of the unswizzled row-major layout while staying
// compatible with global_load_lds' contiguous wave-uniform dest.
#define LDSOFF(R, CC) (((R) << 6) + ((((CC) ^ ((R) & 7))) << 3))

// ---------------------------------------------------------------------------
// Gating + RMS + x->bf16. One wave per row. Writes top-2 ids + weights.
// Gate dots in fp64 so top-k ranking matches numpy ref.
// ---------------------------------------------------------------------------
__global__ __launch_bounds__(256) void gate_kernel(
    const float* __restrict__ x, const float* __restrict__ gw_g,
    bf16* __restrict__ xb, float* __restrict__ rms,
    int* __restrict__ top2, float* __restrict__ c12) {
  __shared__ float gw[NEXP * DIM];
  for (int i = threadIdx.x; i < NEXP * DIM / 4; i += 256)
    *(f32x4*)(gw + i * 4) = *(const f32x4*)(gw_g + i * 4);
  __syncthreads();
  const int lane = threadIdx.x & 63;
  const int wave = threadIdx.x >> 6;
  const int row  = blockIdx.x * 4 + wave;
  const float* xr = x + (size_t)row * DIM;
  f32x4 xv[4];
#pragma unroll
  for (int i = 0; i < 4; i++) xv[i] = *(const f32x4*)(xr + lane * 4 + i * 256);
  float ss = 0.f;
  double dot[8] = {0, 0, 0, 0, 0, 0, 0, 0};
#pragma unroll
  for (int i = 0; i < 4; i++) {
#pragma unroll
    for (int c = 0; c < 4; c++) ss += xv[i][c] * xv[i][c];
#pragma unroll
    for (int e = 0; e < 8; e++) {
      const f32x4 g = *(const f32x4*)(gw + e * DIM + i * 256 + lane * 4);
#pragma unroll
      for (int c = 0; c < 4; c++) dot[e] += (double)xv[i][c] * (double)g[c];
    }
  }
#pragma unroll
  for (int off = 32; off > 0; off >>= 1) {
    ss += __shfl_xor(ss, off, 64);
#pragma unroll
    for (int e = 0; e < 8; e++) dot[e] += __shfl_xor(dot[e], off, 64);
  }
  const float rv = 1.0f / sqrtf(ss * (1.0f / DIM) + 1e-6f);
  if (lane == 0) rms[row] = rv;
  int i1 = 0; double m1 = dot[0];
#pragma unroll
  for (int e = 1; e < 8; e++) if (dot[e] > m1) { m1 = dot[e]; i1 = e; }
  int i2 = 0; double m2 = -1e300;
#pragma unroll
  for (int e = 0; e < 8; e++) if (e != i1 && dot[e] > m2) { m2 = dot[e]; i2 = e; }
  const double t  = exp(m2 - m1);
  if (lane == 0) {
    top2[row] = i1 | (i2 << 8);
    c12[2 * row]     = (float)(1.0 / (1.0 + t));
    c12[2 * row + 1] = (float)(t / (1.0 + t));
  }
#pragma unroll
  for (int i = 0; i < 4; i++) {
    bf16x4 o;
#pragma unroll
    for (int c = 0; c < 4; c++) o[c] = (bf16)xv[i][c];
    *(bf16x4*)(xb + (size_t)row * DIM + lane * 4 + i * 256) = o;
  }
}

// ---------------------------------------------------------------------------
// Histogram + offsets (256-row tiles for gemm1, derived 128-row tiles for
// gemm2). Per-lane register counts, wave shuffle-reduce, 128 LDS atomics.
// ---------------------------------------------------------------------------
__global__ __launch_bounds__(1024) void histoff_kernel(
    const int* __restrict__ top2, int* __restrict__ tileOff256,
    int* __restrict__ tileOff128, int* __restrict__ rowOff) {
  __shared__ int h[8];
  if (threadIdx.x < 8) h[threadIdx.x] = 0;
  __syncthreads();
  int c[8] = {0, 0, 0, 0, 0, 0, 0, 0};
  for (int i = 0; i < B_TOK / 1024; i++) {
    const int pk = top2[threadIdx.x + i * 1024];
    const int e1 = pk & 255, e2 = pk >> 8;
#pragma unroll
    for (int e = 0; e < 8; e++) c[e] += (e1 == e) + (e2 == e);
  }
#pragma unroll
  for (int e = 0; e < 8; e++) {
#pragma unroll
    for (int off = 32; off > 0; off >>= 1) c[e] += __shfl_xor(c[e], off, 64);
  }
  if ((threadIdx.x & 63) == 0) {
#pragma unroll
    for (int e = 0; e < 8; e++) atomicAdd(&h[e], c[e]);
  }
  __syncthreads();
  if (threadIdx.x == 0) {
    int t = 0;
    for (int e = 0; e < 8; e++) {
      tileOff256[e] = t;
      tileOff128[e] = 2 * t;
      rowOff[e]     = t * 256;
      t += (h[e] + 255) >> 8;
    }
    tileOff256[8] = t;
    tileOff128[8] = 2 * t;
  }
}

// ---------------------------------------------------------------------------
// Assign: per-block LDS aggregation, then ONE global atomic per expert per
// block (each counter on its own 128B cache line).
// ---------------------------------------------------------------------------
__global__ __launch_bounds__(256) void assign_kernel(
    const int* __restrict__ top2, const float* __restrict__ c12,
    const int* __restrict__ rowOff, int* __restrict__ cur,
    int* __restrict__ perm, float* __restrict__ cwg) {
  __shared__ int lhist[8];
  __shared__ int lbase[8];
  if (threadIdx.x < 8) lhist[threadIdx.x] = 0;
  __syncthreads();
  const int t = blockIdx.x * 256 + threadIdx.x;
  const int pk = top2[t];
  const int e1 = pk & 255, e2 = pk >> 8;
  const int p1 = atomicAdd(&lhist[e1], 1);
  const int p2 = atomicAdd(&lhist[e2], 1);
  __syncthreads();
  if (threadIdx.x < 8) {
    const int c = lhist[threadIdx.x];
    lbase[threadIdx.x] = c ? atomicAdd(&cur[threadIdx.x * 32], c) : 0;
  }
  __syncthreads();
  const int g1 = rowOff[e1] + lbase[e1] + p1;
  perm[g1] = t; cwg[g1] = c12[2 * t];
  const int g2 = rowOff[e2] + lbase[e2] + p2;
  perm[g2] = t; cwg[g2] = c12[2 * t + 1];
}

// ---------------------------------------------------------------------------
// Weight conversion fp32 -> bf16.
// cvt_kernel: plain (for w2).
// cvt_inter_*: build interleaved B' for gemm1 -- 16-row blocks alternating
// w1 (even) / w3 (odd), so one GEMM produces (h1,h3) in adjacent 16-col
// accumulator fragments. Fractal variant folds the RMSNorm column scale.
// ---------------------------------------------------------------------------
__global__ __launch_bounds__(256) void cvt_kernel(
    const float* __restrict__ src, bf16* __restrict__ dst, int n4) {
  const int i = blockIdx.x * 256 + threadIdx.x;
  if (i >= n4) return;
  f32x4 v = *(const f32x4*)(src + (size_t)i * 4);
  *(bf16x4*)(dst + (size_t)i * 4) = __builtin_convertvector(v, bf16x4);
}

__global__ __launch_bounds__(256) void cvt_inter_fr(
    const float* __restrict__ w1, const float* __restrict__ w3,
    const float* __restrict__ norm, bf16* __restrict__ dst) {
  const int i = blockIdx.x * 256 + threadIdx.x;   // 4*4096*256 f32x4 groups
  const int col4 = i & 255;
  const int rp   = (i >> 8) & 4095;
  const int e    = i >> 20;
  const int blk  = rp >> 4;
  const int sr   = ((blk >> 1) << 4) + (rp & 15);
  const float* src = (blk & 1) ? w3 : w1;
  f32x4 v  = *(const f32x4*)(src + ((size_t)e * HF + sr) * DIM + col4 * 4);
  f32x4 nv = *(const f32x4*)(norm + e * DIM + col4 * 4);
#pragma unroll
  for (int c = 0; c < 4; c++) v[c] *= nv[c];
  *(bf16x4*)(dst + ((size_t)e * 4096 + rp) * DIM + col4 * 4) =
      __builtin_convertvector(v, bf16x4);
}

__global__ __launch_bounds__(256) void cvt_inter_sw(
    const float* __restrict__ w1, const float* __restrict__ w3,
    bf16* __restrict__ dst) {
  const int i = blockIdx.x * 256 + threadIdx.x;   // 4*8192*256 f32x4 groups
  const int col4 = i & 255;
  const int rp   = (i >> 8) & 8191;
  const int e    = i >> 21;
  const int blk  = rp >> 4;
  const int sr   = ((blk >> 1) << 4) + (rp & 15);
  const float* src = (blk & 1) ? w3 : w1;
  f32x4 v = *(const f32x4*)(src + ((size_t)e * HS + sr) * DIM + col4 * 4);
  *(bf16x4*)(dst + ((size_t)e * 8192 + rp) * DIM + col4 * 4) =
      __builtin_convertvector(v, bf16x4);
}

// ---------------------------------------------------------------------------
// Swizzled stage of a (32*nwaves)x64 bf16 tile into LDS, one wave = 32 rows.
// ---------------------------------------------------------------------------
__device__ __forceinline__ void stage_sw(const bf16* __restrict__ g0, int ld,
                                         bf16* s0, int wave, int lane) {
  const int r = lane >> 3;
  const int c = (lane & 7) ^ r;
  const bf16* g = g0 + (size_t)(wave * 32 + r) * ld + c * 8;
  bf16* s = s0 + wave * 2048;
#pragma unroll
  for (int i = 0; i < 4; i++) {
    __builtin_amdgcn_global_load_lds(
        (const __attribute__((address_space(1))) void*)(uintptr_t)(g + (size_t)(i * 8) * ld),
        (__attribute__((address_space(3))) void*)(uintptr_t)(s + i * 512), 16, 0, 0);
  }
}

// ---------------------------------------------------------------------------
// GEMM1: 256x256 tile, BK=64, 8 waves (2M x 4N), double-buffered LDS
// (128 KB). T3-minimum pipeline with T4 counted drain: per K-step issue
// next-tile global_load_lds FIRST, compute current tile, then ONE
// asm vmcnt(0) + raw s_barrier at the end (prefetch latency hides under
// the 64-MFMA compute phase; __syncthreads' forced pre-compute drain gone).
// B' is the 16-row-interleaved (w1|w3) matrix, so acc n-frags alternate
// h1/h3 of the same G column block. G = silu(s*H1)*(s*H3).
// ---------------------------------------------------------------------------
__global__ __launch_bounds__(512, 2) void gemm1_kernel(
    const bf16* __restrict__ xb, const int* __restrict__ perm,
    const float* __restrict__ rms,
    const bf16* __restrict__ fwi, const bf16* __restrict__ swi,
    const int* __restrict__ tileOff256, bf16* __restrict__ G, int chunk) {
  const int bt = chunk * CT1 + blockIdx.y;
  int toff[9];
#pragma unroll
  for (int i = 0; i < 9; i++) toff[i] = tileOff256[i];
  if (bt >= toff[8]) return;
  int e = 0;
#pragma unroll
  for (int i = 1; i < 8; i++) if (bt >= toff[i]) e = i;
  const bool isfr = (e < NFR);
  const int nt = isfr ? 16 : 32;            // N' = 4096 (fr) / 8192 (sw)
  if ((int)blockIdx.x >= nt) return;
  const bf16* Bp = isfr ? fwi + (size_t)e * 4096 * DIM
                        : swi + (size_t)(e - NFR) * 8192 * DIM;

  __shared__ __attribute__((aligned(16))) bf16 As[2 * 16384];
  __shared__ __attribute__((aligned(16))) bf16 Bs[2 * 16384];
  const int lane = threadIdx.x & 63, wave = threadIdx.x >> 6;
  const int wm = wave >> 2, wn = wave & 3;
  const int g0  = bt * 256;
  const int n0p = blockIdx.x * 256;         // B' row offset

  // staging source pointers (gathered A rows; regular B' rows)
  const int rA = lane >> 3;
  const int cA = (lane & 7) ^ rA;
  const bf16* Ag[4];
#pragma unroll
  for (int i = 0; i < 4; i++) {
    int tk = perm[g0 + wave * 32 + i * 8 + rA];
    if (tk < 0) tk = 0;
    Ag[i] = xb + (size_t)tk * DIM + cA * 8;
  }
  const bf16* Bg = Bp + (size_t)(n0p + wave * 32 + rA) * DIM + cA * 8;

  f32x4 acc[8][4];
#pragma unroll
  for (int i = 0; i < 8; i++)
#pragma unroll
    for (int j = 0; j < 4; j++) { f32x4 z = {0.f, 0.f, 0.f, 0.f}; acc[i][j] = z; }
  const int lr = lane & 15, lq = lane >> 4;

  auto stage = [&](int buf, int k0) {
    bf16* sa = As + buf * 16384 + wave * 2048;
    bf16* sb = Bs + buf * 16384 + wave * 2048;
#pragma unroll
    for (int i = 0; i < 4; i++) {
      __builtin_amdgcn_global_load_lds(
          (const __attribute__((address_space(1))) void*)(uintptr_t)(Ag[i] + k0),
          (__attribute__((address_space(3))) void*)(uintptr_t)(sa + i * 512), 16, 0, 0);
    }
#pragma unroll
    for (int i = 0; i < 4; i++) {
      __builtin_amdgcn_global_load_lds(
          (const __attribute__((address_space(1))) void*)(uintptr_t)(Bg + (size_t)(i * 8) * DIM + k0),
          (__attribute__((address_space(3))) void*)(uintptr_t)(sb + i * 512), 16, 0, 0);
    }
  };
  auto compute = [&](int buf) {
    const bf16* Ab = As + buf * 16384;
    const bf16* Bb = Bs + buf * 16384;
#pragma unroll
    for (int ks = 0; ks < 2; ks++) {
      bf16x8 af[8], bfv[4];
#pragma unroll
      for (int mi = 0; mi < 8; mi++)
        af[mi] = *(const bf16x8*)(Ab + LDSOFF(wm * 128 + mi * 16 + lr, ks * 4 + lq));
#pragma unroll
      for (int ni = 0; ni < 4; ni++)
        bfv[ni] = *(const bf16x8*)(Bb + LDSOFF(wn * 64 + ni * 16 + lr, ks * 4 + lq));
      __builtin_amdgcn_s_setprio(1);
#pragma unroll
      for (int mi = 0; mi < 8; mi++)
#pragma unroll
        for (int ni = 0; ni < 4; ni++)
          acc[mi][ni] = __builtin_amdgcn_mfma_f32_16x16x32_bf16(af[mi], bfv[ni], acc[mi][ni], 0, 0, 0);
      __builtin_amdgcn_s_setprio(0);
    }
  };

  stage(0, 0);
  asm volatile("s_waitcnt vmcnt(0)" ::: "memory");
  __builtin_amdgcn_s_barrier();
#pragma unroll 1
  for (int t = 0; t < 15; t++) {
    const int cur = t & 1;
    stage(cur ^ 1, (t + 1) * 64);   // prefetch issued BEFORE compute
    compute(cur);                   // ~64 MFMA hide the prefetch latency
    asm volatile("s_waitcnt vmcnt(0)" ::: "memory");
    __builtin_amdgcn_s_barrier();   // one barrier per K-step
  }
  compute(1);                       // tile 15 lives in buffer 1

  // epilogue: C/D layout col=lane&15, row=(lane>>4)*4+r [m89/m91]
  const int gh = n0p >> 1;                   // base G column of this block
#pragma unroll
  for (int mi = 0; mi < 8; mi++) {
#pragma unroll
    for (int r = 0; r < 4; r++) {
      const int row_l = wm * 128 + mi * 16 + lq * 4 + r;
      float s = 1.0f;
      if (isfr) {
        int tok = perm[g0 + row_l];
        s = rms[tok < 0 ? 0 : tok];
      }
      bf16* Grow = G + (size_t)(blockIdx.y * 256 + row_l) * HS;
#pragma unroll
      for (int nh = 0; nh < 2; nh++) {
        const float h1 = acc[mi][2 * nh][r] * s;
        const float h3 = acc[mi][2 * nh + 1][r] * s;
        const int col = gh + wn * 32 + nh * 16 + lr;
        Grow[col] = (bf16)(h1 / (1.0f + __expf(-h1)) * h3);
      }
    }
  }
}

// ---------------------------------------------------------------------------
// GEMM2: Y = G @ W2^T (N=1024), 128x128 tiles, double-buffered with the same
// T3/T4 one-barrier counted-drain pipeline. Scatter-add to out with fused
// epilogue:
//   fractal: out[tok] += cw*(gamma[col]*(rms[tok]*x*norm[col] + Y) + x)
//   plain:   out[tok] += cw*Y
// ---------------------------------------------------------------------------
__global__ __launch_bounds__(256, 2) void gemm2_kernel(
    const bf16* __restrict__ G, const int* __restrict__ perm,
    const float* __restrict__ cwg, const float* __restrict__ rms,
    const float* __restrict__ gamma_all, const float* __restrict__ norm_all,
    const float* __restrict__ x,
    const bf16* __restrict__ fw2, const bf16* __restrict__ s2b,
    const int* __restrict__ tileOff128, float* __restrict__ out, int chunk) {
  const int bt = chunk * CT2 + blockIdx.y;
  int toff[9];
#pragma unroll
  for (int i = 0; i < 9; i++) toff[i] = tileOff128[i];
  if (bt >= toff[8]) return;
  int e = 0;
#pragma unroll
  for (int i = 1; i < 8; i++) if (bt >= toff[i]) e = i;
  const bool isfr = (e < NFR);
  const int K = isfr ? HF : HS;
  const bf16* Bw = isfr ? fw2 + (size_t)e * DIM * HF : s2b + (size_t)(e - NFR) * DIM * HS;

  __shared__ __attribute__((aligned(16))) bf16 As[2 * 8192];
  __shared__ __attribute__((aligned(16))) bf16 Bs[2 * 8192];
  const int lane = threadIdx.x & 63, wave = threadIdx.x >> 6;
  const int wm = wave >> 1, wn = wave & 1;
  const int n0 = blockIdx.x * 128;
  f32x4 acc[4][4];
#pragma unroll
  for (int i = 0; i < 4; i++)
#pragma unroll
    for (int j = 0; j < 4; j++) { f32x4 z = {0.f, 0.f, 0.f, 0.f}; acc[i][j] = z; }
  const bf16* Ab = G + (size_t)(blockIdx.y * 128) * HS;   // chunk-local rows
  const bf16* Bb = Bw + (size_t)n0 * K;
  const int lr = lane & 15, lq = lane >> 4;

  auto compute = [&](int buf) {
    const bf16* Ap = As + buf * 8192;
    const bf16* Bp = Bs + buf * 8192;
#pragma unroll
    for (int ks = 0; ks < 2; ks++) {
      bf16x8 af[4], bf_[4];
#pragma unroll
      for (int mi = 0; mi < 4; mi++)
        af[mi] = *(const bf16x8*)(Ap + LDSOFF(wm * 64 + mi * 16 + lr, ks * 4 + lq));
#pragma unroll
      for (int ni = 0; ni < 4; ni++)
        bf_[ni] = *(const bf16x8*)(Bp + LDSOFF(wn * 64 + ni * 16 + lr, ks * 4 + lq));
      __builtin_amdgcn_s_setprio(1);
#pragma unroll
      for (int mi = 0; mi < 4; mi++)
#pragma unroll
        for (int ni = 0; ni < 4; ni++)
          acc[mi][ni] = __builtin_amdgcn_mfma_f32_16x16x32_bf16(af[mi], bf_[ni], acc[mi][ni], 0, 0, 0);
      __builtin_amdgcn_s_setprio(0);
    }
  };

  stage_sw(Ab, HS, As, wave, lane);
  stage_sw(Bb, K, Bs, wave, lane);
  asm volatile("s_waitcnt vmcnt(0)" ::: "memory");
  __builtin_amdgcn_s_barrier();
  const int NTK = K >> 6;
#pragma unroll 1
  for (int t = 0; t < NTK - 1; t++) {
    const int cur = t & 1;
    const int k1 = (t + 1) << 6;
    stage_sw(Ab + k1, HS, As + (cur ^ 1) * 8192, wave, lane);
    stage_sw(Bb + k1, K, Bs + (cur ^ 1) * 8192, wave, lane);
    compute(cur);
    asm volatile("s_waitcnt vmcnt(0)" ::: "memory");
    __builtin_amdgcn_s_barrier();
  }
  compute((NTK - 1) & 1);

#pragma unroll
  for (int mi = 0; mi < 4; mi++) {
#pragma unroll
    for (int r = 0; r < 4; r++) {
      const int row_l = wm * 64 + mi * 16 + lq * 4 + r;
      const int g_row = bt * 128 + row_l;
      const int tok = perm[g_row];
      if (tok < 0) continue;
      const float cw = cwg[g_row];
      const float rv = rms[tok];
#pragma unroll
      for (int ni = 0; ni < 4; ni++) {
        const int col = n0 + wn * 64 + ni * 16 + lr;
        const float a = acc[mi][ni][r];
        float res;
        if (isfr) {
          const float xvv = x[(size_t)tok * DIM + col];
          res = cw * (gamma_all[e * DIM + col] * (rv * xvv * norm_all[e * DIM + col] + a) + xvv);
        } else {
          res = cw * a;
        }
        atomicAdd(&out[(size_t)tok * DIM + col], res);
      }
    }
  }
}

// ---------------------------------------------------------------------------
extern "C" void kernel_launch(void* const* d_in, const int* in_sizes, int n_in,
                              void* d_out, int out_size, void* d_ws, size_t ws_size,
                              hipStream_t stream) {
  const float* x        = (const float*)d_in[0];
  const float* gate_w   = (const float*)d_in[1];
  const float* fr_norm  = (const float*)d_in[2];
  const float* fr_gamma = (const float*)d_in[3];
  const float* fr_w1    = (const float*)d_in[4];
  const float* fr_w2    = (const float*)d_in[5];
  const float* fr_w3    = (const float*)d_in[6];
  const float* sw_w1    = (const float*)d_in[7];
  const float* sw_w2    = (const float*)d_in[8];
  const float* sw_w3    = (const float*)d_in[9];
  float* out = (float*)d_out;

  char* ws = (char*)d_ws;                        // ~286.3 MB total
  bf16*  xb    = (bf16*)(ws);                    // 64 MB
  bf16*  fwi   = (bf16*)(ws + 67108864);         // 32 MB (fr w1|w3 interleaved, *norm)
  bf16*  fw2   = (bf16*)(ws + 100663296);        // 16 MB
  bf16*  swi   = (bf16*)(ws + 117440512);        // 64 MB (sw w1|w3 interleaved)
  bf16*  s2b   = (bf16*)(ws + 184549376);        // 32 MB
  bf16*  G     = (bf16*)(ws + 218103808);        // 64 MB (8192 x 4096)
  float* rmsb  = (float*)(ws + 285212672);       // 128 KB
  int*   top2  = (int*)  (ws + 285343744);       // 128 KB
  float* c12   = (float*)(ws + 285474816);       // 256 KB
  int*   perm  = (int*)  (ws + 285736960);       // 264 KB
  float* cwg   = (float*)(ws + 286007296);       // 264 KB
  int*   cur   = (int*)  (ws + 286277632);       // 1 KB (8 counters, 128B apart)
  int*   tileOff256 = (int*)(ws + 286278656);    // 64 B
  int*   tileOff128 = (int*)(ws + 286278720);    // 64 B
  int*   rowOff     = (int*)(ws + 286278784);    // 64 B

  hipMemsetAsync(d_out, 0, (size_t)out_size * sizeof(float), stream);
  hipMemsetAsync(cur, 0, 1024, stream);
  hipMemsetAsync(perm, 0xFF, PADROWS * 4, stream);

  gate_kernel<<<B_TOK / 4, 256, 0, stream>>>(x, gate_w, xb, rmsb, top2, c12);
  histoff_kernel<<<1, 1024, 0, stream>>>(top2, tileOff256, tileOff128, rowOff);
  assign_kernel<<<B_TOK / 256, 256, 0, stream>>>(top2, c12, rowOff, cur, perm, cwg);

  cvt_inter_fr<<<16384, 256, 0, stream>>>(fr_w1, fr_w3, fr_norm, fwi);
  cvt_kernel<<<8192, 256, 0, stream>>>(fr_w2, fw2, 2097152);
  cvt_inter_sw<<<32768, 256, 0, stream>>>(sw_w1, sw_w3, swi);
  cvt_kernel<<<16384, 256, 0, stream>>>(sw_w2, s2b, 4194304);

  for (int c = 0; c < NCH; c++) {
    gemm1_kernel<<<dim3(32, CT1), 512, 0, stream>>>(
        xb, perm, rmsb, fwi, swi, tileOff256, G, c);
    gemm2_kernel<<<dim3(8, CT2), 256, 0, stream>>>(
        G, perm, cwg, rmsb, fr_gamma, fr_norm, x, fw2, s2b, tileOff128, out, c);
  }
}